// Round 1
// baseline (1904.422 us; speedup 1.0000x reference)
//
#include <hip/hip_runtime.h>
#include <cfloat>

#define NROWS 131072
#define DIM 256
#define KCODES 512
#define DECAYF 0.99f
#define OMDECAYF 0.01f
#define EPSF 1e-5f
#define BATCHF 32.0f

#define BM 128
#define BN 128
#define BD 16

// ---------------- ws layout (bytes) ----------------
// 0      : cnorm    512 f
// 2048   : counts   512 i   (memset 0 each launch)
// 4096   : base     512 i
// 6144   : cursor   512 i
// 8192   : loss_sum 1 f     (memset 0 each launch)
// 12288  : enc_int  131072 i
// 536576 : rowlist  131072 i
// total ~1.06 MB

__global__ __launch_bounds__(256) void cnorm_kernel(const float* __restrict__ cb,
                                                    float* __restrict__ cnorm) {
  int k = blockIdx.x;
  int t = threadIdx.x;
  float v = cb[(size_t)k * DIM + t];
  float s = v * v;
  for (int off = 32; off > 0; off >>= 1) s += __shfl_down(s, off);
  __shared__ float p[4];
  if ((t & 63) == 0) p[t >> 6] = s;
  __syncthreads();
  if (t == 0) cnorm[k] = (p[0] + p[1]) + (p[2] + p[3]);
}

// Fused distance-GEMM + argmin + histogram.
// Block: 256 threads = 16(tx: codes) x 16(ty: rows); micro-tile 8 rows x 8 codes.
__global__ __launch_bounds__(256) void argmin_kernel(
    const float* __restrict__ z, const float* __restrict__ cb,
    const float* __restrict__ cnorm, int* __restrict__ enc_int,
    float* __restrict__ enc_out, int* __restrict__ counts) {
  __shared__ float As[BD][BM + 4];
  __shared__ float Bs[BD][BN + 4];
  __shared__ int hist[KCODES];
  __shared__ float redv[BM][17];
  __shared__ int redi[BM][17];

  const int tid = threadIdx.x;
  const int tx = tid & 15;
  const int ty = tid >> 4;

  hist[tid] = 0;
  hist[tid + 256] = 0;

  const float* zblk = z + (size_t)blockIdx.x * BM * DIM;

  float minv[8];
  int mini[8];
#pragma unroll
  for (int r = 0; r < 8; ++r) { minv[r] = FLT_MAX; mini[r] = 0; }

  for (int cc = 0; cc < KCODES / BN; ++cc) {
    float acc[8][8];
#pragma unroll
    for (int r = 0; r < 8; ++r)
#pragma unroll
      for (int j = 0; j < 8; ++j) acc[r][j] = 0.f;

    for (int dc = 0; dc < DIM / BD; ++dc) {
      __syncthreads();
#pragma unroll
      for (int i = 0; i < 2; ++i) {
        int f4 = tid + i * 256;
        int r = f4 >> 2;
        int d4 = (f4 & 3) << 2;
        float4 av = *(const float4*)&zblk[(size_t)r * DIM + dc * BD + d4];
        As[d4 + 0][r] = av.x; As[d4 + 1][r] = av.y;
        As[d4 + 2][r] = av.z; As[d4 + 3][r] = av.w;
        float4 bv = *(const float4*)&cb[(size_t)(cc * BN + r) * DIM + dc * BD + d4];
        Bs[d4 + 0][r] = bv.x; Bs[d4 + 1][r] = bv.y;
        Bs[d4 + 2][r] = bv.z; Bs[d4 + 3][r] = bv.w;
      }
      __syncthreads();
#pragma unroll 4
      for (int dd = 0; dd < BD; ++dd) {
        float a[8], b[8];
        *(float4*)&a[0] = *(const float4*)&As[dd][ty * 8];
        *(float4*)&a[4] = *(const float4*)&As[dd][ty * 8 + 4];
        *(float4*)&b[0] = *(const float4*)&Bs[dd][tx * 8];
        *(float4*)&b[4] = *(const float4*)&Bs[dd][tx * 8 + 4];
#pragma unroll
        for (int r = 0; r < 8; ++r)
#pragma unroll
          for (int j = 0; j < 8; ++j) acc[r][j] = fmaf(a[r], b[j], acc[r][j]);
      }
    }
    // score = ||c||^2 - 2*dot  (||x||^2 constant per row, irrelevant for argmin)
#pragma unroll
    for (int j = 0; j < 8; ++j) {
      int code = cc * BN + tx * 8 + j;
      float cn = cnorm[code];
#pragma unroll
      for (int r = 0; r < 8; ++r) {
        float s = cn - 2.f * acc[r][j];
        if (s < minv[r]) { minv[r] = s; mini[r] = code; }  // strict <: first occurrence wins
      }
    }
  }

  __syncthreads();
#pragma unroll
  for (int r = 0; r < 8; ++r) {
    redv[ty * 8 + r][tx] = minv[r];
    redi[ty * 8 + r][tx] = mini[r];
  }
  __syncthreads();
  if (tid < BM) {
    float bv = redv[tid][0];
    int bi = redi[tid][0];
#pragma unroll
    for (int t = 1; t < 16; ++t) {
      float v = redv[tid][t];
      int ii = redi[tid][t];
      if (v < bv || (v == bv && ii < bi)) { bv = v; bi = ii; }
    }
    int row = blockIdx.x * BM + tid;
    enc_int[row] = bi;
    enc_out[row] = (float)bi;
    atomicAdd(&hist[bi], 1);
  }
  __syncthreads();
  atomicAdd(&counts[tid], hist[tid]);
  atomicAdd(&counts[tid + 256], hist[tid + 256]);
}

// code gather -> code_ste output, fused commitment-loss partial sums
__global__ __launch_bounds__(256) void gather_kernel(
    const float* __restrict__ z, const float* __restrict__ cb,
    const int* __restrict__ enc, float* __restrict__ code_out,
    float* __restrict__ loss_sum) {
  int e4 = blockIdx.x * 256 + threadIdx.x;
  int row = e4 >> 6;        // 64 float4 per row
  int d4 = (e4 & 63) << 2;
  int k = enc[row];
  float4 zv = *(const float4*)&z[(size_t)e4 * 4];
  float4 cv = *(const float4*)&cb[(size_t)k * DIM + d4];
  *(float4*)&code_out[(size_t)e4 * 4] = cv;
  float dx = zv.x - cv.x, dy = zv.y - cv.y, dz = zv.z - cv.z, dw = zv.w - cv.w;
  float s = dx * dx + dy * dy + dz * dz + dw * dw;
  for (int off = 32; off > 0; off >>= 1) s += __shfl_down(s, off);
  __shared__ float p[4];
  int t = threadIdx.x;
  if ((t & 63) == 0) p[t >> 6] = s;
  __syncthreads();
  if (t == 0) atomicAdd(loss_sum, (p[0] + p[1]) + (p[2] + p[3]));
}

// single block: n_new + exclusive prefix sum of counts
__global__ __launch_bounds__(512) void scan_kernel(
    const int* __restrict__ counts, const float* __restrict__ n_i,
    float* __restrict__ n_new_out, int* __restrict__ base,
    int* __restrict__ cursor) {
  __shared__ int sd[KCODES];
  int t = threadIdx.x;
  int c = counts[t];
  float nn = DECAYF * n_i[t] + OMDECAYF * (float)c;
  nn = (nn + EPSF) / (BATCHF + (float)KCODES * EPSF) * BATCHF;
  n_new_out[t] = nn;
  sd[t] = c;
  __syncthreads();
  for (int off = 1; off < KCODES; off <<= 1) {
    int v = (t >= off) ? sd[t - off] : 0;
    __syncthreads();
    sd[t] += v;
    __syncthreads();
  }
  int excl = sd[t] - c;
  base[t] = excl;
  cursor[t] = excl;
}

__global__ __launch_bounds__(256) void scatter_kernel(
    const int* __restrict__ enc, int* __restrict__ cursor,
    int* __restrict__ rowlist) {
  int row = blockIdx.x * 256 + threadIdx.x;
  int k = enc[row];
  int pos = atomicAdd(&cursor[k], 1);
  rowlist[pos] = row;
}

// one block per code: segment-sum assigned rows, EMA update, finalize loss
__global__ __launch_bounds__(256) void update_kernel(
    const float* __restrict__ z, const int* __restrict__ rowlist,
    const int* __restrict__ base, const int* __restrict__ counts,
    const float* __restrict__ e_i, const float* __restrict__ n_new,
    float* __restrict__ e_new_out, float* __restrict__ cbn_out,
    const float* __restrict__ loss_sum, float* __restrict__ loss_out) {
  int k = blockIdx.x;
  int d = threadIdx.x;
  int b0 = base[k], cnt = counts[k];
  float s0 = 0, s1 = 0, s2 = 0, s3 = 0;
  int i = 0;
  for (; i + 4 <= cnt; i += 4) {
    int r0 = rowlist[b0 + i], r1 = rowlist[b0 + i + 1];
    int r2 = rowlist[b0 + i + 2], r3 = rowlist[b0 + i + 3];
    s0 += z[(size_t)r0 * DIM + d];
    s1 += z[(size_t)r1 * DIM + d];
    s2 += z[(size_t)r2 * DIM + d];
    s3 += z[(size_t)r3 * DIM + d];
  }
  for (; i < cnt; ++i) {
    int r = rowlist[b0 + i];
    s0 += z[(size_t)r * DIM + d];
  }
  float s = (s0 + s1) + (s2 + s3);
  float e = DECAYF * e_i[(size_t)k * DIM + d] + OMDECAYF * s;
  e_new_out[(size_t)k * DIM + d] = e;
  cbn_out[(size_t)k * DIM + d] = e / n_new[k];
  if (k == 0 && d == 0) loss_out[0] = 0.25f * loss_sum[0] / 33554432.0f;
}

extern "C" void kernel_launch(void* const* d_in, const int* in_sizes, int n_in,
                              void* d_out, int out_size, void* d_ws, size_t ws_size,
                              hipStream_t stream) {
  const float* z = (const float*)d_in[0];
  const float* cb = (const float*)d_in[1];
  const float* n_i = (const float*)d_in[2];
  const float* e_i = (const float*)d_in[3];

  float* out = (float*)d_out;
  float* out_code = out;                    // 33554432
  float* out_loss = out + 33554432;         // 1
  float* out_enc = out + 33554433;          // 131072
  float* out_cbn = out + 33685505;          // 131072
  float* out_nn = out + 33816577;           // 512
  float* out_en = out + 33817089;           // 131072

  char* ws = (char*)d_ws;
  float* cnorm = (float*)(ws + 0);
  int* counts = (int*)(ws + 2048);
  int* base = (int*)(ws + 4096);
  int* cursor = (int*)(ws + 6144);
  float* loss = (float*)(ws + 8192);
  int* enc_int = (int*)(ws + 12288);
  int* rowlist = (int*)(ws + 536576);

  // zero counts/base/cursor/loss (ws is poisoned 0xAA before each launch)
  hipMemsetAsync(ws + 2048, 0, 8192 - 2048 + 4, stream);

  cnorm_kernel<<<KCODES, 256, 0, stream>>>(cb, cnorm);
  argmin_kernel<<<NROWS / BM, 256, 0, stream>>>(z, cb, cnorm, enc_int, out_enc, counts);
  gather_kernel<<<(NROWS * (DIM / 4)) / 256, 256, 0, stream>>>(z, cb, enc_int, out_code, loss);
  scan_kernel<<<1, KCODES, 0, stream>>>(counts, n_i, out_nn, base, cursor);
  scatter_kernel<<<NROWS / 256, 256, 0, stream>>>(enc_int, cursor, rowlist);
  update_kernel<<<KCODES, 256, 0, stream>>>(z, rowlist, base, counts, e_i, out_nn,
                                            out_en, out_cbn, loss, out_loss);
}

// Round 2
// 1047.390 us; speedup vs baseline: 1.8183x; 1.8183x over previous
//
#include <hip/hip_runtime.h>
#include <cfloat>

#define NROWS 131072
#define DIM 256
#define KCODES 512
#define DECAYF 0.99f
#define OMDECAYF 0.01f
#define EPSF 1e-5f
#define BATCHF 32.0f

#define BM 128
#define BN 128
#define BD 16
#define CHUNK 128
#define ROWMASK 0x1FFFF

// ---------------- ws layout (bytes) ----------------
// 0      : cnorm    512 f
// 2048   : counts   512 i   (memset 0 each launch)
// 6144   : cursor   512 i   (written by scan)
// 8192   : loss_sum 1 f     (memset 0 each launch)
// 12288  : enc_int  131072 i
// 536576 : rowlist  131072 i  (packed (code<<17)|row, sorted by code)

// cnorm + init e_new output with decay*e_i  (512 blocks x 256 = K x D exactly)
__global__ __launch_bounds__(256) void cnorm_kernel(const float* __restrict__ cb,
                                                    const float* __restrict__ e_i,
                                                    float* __restrict__ cnorm,
                                                    float* __restrict__ en_out) {
  int k = blockIdx.x;
  int t = threadIdx.x;
  size_t idx = (size_t)k * DIM + t;
  float v = cb[idx];
  en_out[idx] = DECAYF * e_i[idx];
  float s = v * v;
  for (int off = 32; off > 0; off >>= 1) s += __shfl_down(s, off);
  __shared__ float p[4];
  if ((t & 63) == 0) p[t >> 6] = s;
  __syncthreads();
  if (t == 0) cnorm[k] = (p[0] + p[1]) + (p[2] + p[3]);
}

// Fused distance-GEMM + argmin + histogram.
// Block: 256 threads = 16(tx: codes) x 16(ty: rows); micro-tile 8 rows x 8 codes.
__global__ __launch_bounds__(256) void argmin_kernel(
    const float* __restrict__ z, const float* __restrict__ cb,
    const float* __restrict__ cnorm, int* __restrict__ enc_int,
    float* __restrict__ enc_out, int* __restrict__ counts) {
  __shared__ float As[BD][BM + 4];
  __shared__ float Bs[BD][BN + 4];
  __shared__ int hist[KCODES];
  __shared__ float redv[BM][17];
  __shared__ int redi[BM][17];

  const int tid = threadIdx.x;
  const int tx = tid & 15;
  const int ty = tid >> 4;

  hist[tid] = 0;
  hist[tid + 256] = 0;

  const float* zblk = z + (size_t)blockIdx.x * BM * DIM;

  float minv[8];
  int mini[8];
#pragma unroll
  for (int r = 0; r < 8; ++r) { minv[r] = FLT_MAX; mini[r] = 0; }

  for (int cc = 0; cc < KCODES / BN; ++cc) {
    float acc[8][8];
#pragma unroll
    for (int r = 0; r < 8; ++r)
#pragma unroll
      for (int j = 0; j < 8; ++j) acc[r][j] = 0.f;

    for (int dc = 0; dc < DIM / BD; ++dc) {
      __syncthreads();
#pragma unroll
      for (int i = 0; i < 2; ++i) {
        int f4 = tid + i * 256;
        int r = f4 >> 2;
        int d4 = (f4 & 3) << 2;
        float4 av = *(const float4*)&zblk[(size_t)r * DIM + dc * BD + d4];
        As[d4 + 0][r] = av.x; As[d4 + 1][r] = av.y;
        As[d4 + 2][r] = av.z; As[d4 + 3][r] = av.w;
        float4 bv = *(const float4*)&cb[(size_t)(cc * BN + r) * DIM + dc * BD + d4];
        Bs[d4 + 0][r] = bv.x; Bs[d4 + 1][r] = bv.y;
        Bs[d4 + 2][r] = bv.z; Bs[d4 + 3][r] = bv.w;
      }
      __syncthreads();
#pragma unroll 4
      for (int dd = 0; dd < BD; ++dd) {
        float a[8], b[8];
        *(float4*)&a[0] = *(const float4*)&As[dd][ty * 8];
        *(float4*)&a[4] = *(const float4*)&As[dd][ty * 8 + 4];
        *(float4*)&b[0] = *(const float4*)&Bs[dd][tx * 8];
        *(float4*)&b[4] = *(const float4*)&Bs[dd][tx * 8 + 4];
#pragma unroll
        for (int r = 0; r < 8; ++r)
#pragma unroll
          for (int j = 0; j < 8; ++j) acc[r][j] = fmaf(a[r], b[j], acc[r][j]);
      }
    }
    // score = ||c||^2 - 2*dot  (||x||^2 constant per row, irrelevant for argmin)
#pragma unroll
    for (int j = 0; j < 8; ++j) {
      int code = cc * BN + tx * 8 + j;
      float cn = cnorm[code];
#pragma unroll
      for (int r = 0; r < 8; ++r) {
        float s = cn - 2.f * acc[r][j];
        if (s < minv[r]) { minv[r] = s; mini[r] = code; }  // strict <: first occurrence wins
      }
    }
  }

  __syncthreads();
#pragma unroll
  for (int r = 0; r < 8; ++r) {
    redv[ty * 8 + r][tx] = minv[r];
    redi[ty * 8 + r][tx] = mini[r];
  }
  __syncthreads();
  if (tid < BM) {
    float bv = redv[tid][0];
    int bi = redi[tid][0];
#pragma unroll
    for (int t = 1; t < 16; ++t) {
      float v = redv[tid][t];
      int ii = redi[tid][t];
      if (v < bv || (v == bv && ii < bi)) { bv = v; bi = ii; }
    }
    int row = blockIdx.x * BM + tid;
    enc_int[row] = bi;
    enc_out[row] = (float)bi;
    atomicAdd(&hist[bi], 1);
  }
  __syncthreads();
  atomicAdd(&counts[tid], hist[tid]);
  atomicAdd(&counts[tid + 256], hist[tid + 256]);
}

// code gather -> code_ste output, fused commitment-loss partial sums
__global__ __launch_bounds__(256) void gather_kernel(
    const float* __restrict__ z, const float* __restrict__ cb,
    const int* __restrict__ enc, float* __restrict__ code_out,
    float* __restrict__ loss_sum) {
  int e4 = blockIdx.x * 256 + threadIdx.x;
  int row = e4 >> 6;        // 64 float4 per row
  int d4 = (e4 & 63) << 2;
  int k = enc[row];
  float4 zv = *(const float4*)&z[(size_t)e4 * 4];
  float4 cv = *(const float4*)&cb[(size_t)k * DIM + d4];
  *(float4*)&code_out[(size_t)e4 * 4] = cv;
  float dx = zv.x - cv.x, dy = zv.y - cv.y, dz = zv.z - cv.z, dw = zv.w - cv.w;
  float s = dx * dx + dy * dy + dz * dz + dw * dw;
  for (int off = 32; off > 0; off >>= 1) s += __shfl_down(s, off);
  __shared__ float p[4];
  int t = threadIdx.x;
  if ((t & 63) == 0) p[t >> 6] = s;
  __syncthreads();
  if (t == 0) atomicAdd(loss_sum, (p[0] + p[1]) + (p[2] + p[3]));
}

// single block: n_new + exclusive prefix sum of counts -> cursor
__global__ __launch_bounds__(512) void scan_kernel(
    const int* __restrict__ counts, const float* __restrict__ n_i,
    float* __restrict__ n_new_out, int* __restrict__ cursor) {
  __shared__ int sd[KCODES];
  int t = threadIdx.x;
  int c = counts[t];
  float nn = DECAYF * n_i[t] + OMDECAYF * (float)c;
  nn = (nn + EPSF) / (BATCHF + (float)KCODES * EPSF) * BATCHF;
  n_new_out[t] = nn;
  sd[t] = c;
  __syncthreads();
  for (int off = 1; off < KCODES; off <<= 1) {
    int v = (t >= off) ? sd[t - off] : 0;
    __syncthreads();
    sd[t] += v;
    __syncthreads();
  }
  cursor[t] = sd[t] - c;
}

// LDS-aggregated counting-sort scatter: writes packed (code<<17)|row.
// Caps same-address global-atomic serialization at <=512 per counter.
__global__ __launch_bounds__(256) void scatter_kernel(
    const int* __restrict__ enc, int* __restrict__ cursor,
    int* __restrict__ rowlist) {
  __shared__ int lcnt[KCODES];
  __shared__ int lbase[KCODES];
  int tid = threadIdx.x;
  int row = blockIdx.x * 256 + tid;
  lcnt[tid] = 0;
  lcnt[tid + 256] = 0;
  __syncthreads();
  int k = enc[row];
  int p = atomicAdd(&lcnt[k], 1);
  __syncthreads();
  int c0 = lcnt[tid];
  if (c0) lbase[tid] = atomicAdd(&cursor[tid], c0);
  int c1 = lcnt[tid + 256];
  if (c1) lbase[tid + 256] = atomicAdd(&cursor[tid + 256], c1);
  __syncthreads();
  rowlist[lbase[k] + p] = (k << 17) | row;
}

// Load-balanced segmented sum over sorted rowlist: 128 rows per block,
// run-length accumulate in registers, one atomicAdd per run per dim.
__global__ __launch_bounds__(256) void chunk_sum_kernel(
    const float* __restrict__ z, const int* __restrict__ rowlist,
    float* __restrict__ en_out) {
  __shared__ int rl[CHUNK];
  int tid = threadIdx.x;
  int d = tid;
  if (tid < CHUNK) rl[tid] = rowlist[blockIdx.x * CHUNK + tid];
  __syncthreads();
  int cur = rl[0] >> 17;
  float s = 0.f;
  for (int i = 0; i < CHUNK; i += 4) {
    int p0 = rl[i + 0], p1 = rl[i + 1], p2 = rl[i + 2], p3 = rl[i + 3];
    // 4 independent coalesced row loads (latency overlap)
    float v0 = z[(size_t)(p0 & ROWMASK) * DIM + d];
    float v1 = z[(size_t)(p1 & ROWMASK) * DIM + d];
    float v2 = z[(size_t)(p2 & ROWMASK) * DIM + d];
    float v3 = z[(size_t)(p3 & ROWMASK) * DIM + d];
    int k;
    k = p0 >> 17;
    if (k != cur) { atomicAdd(&en_out[(size_t)cur * DIM + d], OMDECAYF * s); s = 0.f; cur = k; }
    s += v0;
    k = p1 >> 17;
    if (k != cur) { atomicAdd(&en_out[(size_t)cur * DIM + d], OMDECAYF * s); s = 0.f; cur = k; }
    s += v1;
    k = p2 >> 17;
    if (k != cur) { atomicAdd(&en_out[(size_t)cur * DIM + d], OMDECAYF * s); s = 0.f; cur = k; }
    s += v2;
    k = p3 >> 17;
    if (k != cur) { atomicAdd(&en_out[(size_t)cur * DIM + d], OMDECAYF * s); s = 0.f; cur = k; }
    s += v3;
  }
  atomicAdd(&en_out[(size_t)cur * DIM + d], OMDECAYF * s);
}

// cbn = e_new / n_new; finalize loss scalar
__global__ __launch_bounds__(256) void finalize_kernel(
    const float* __restrict__ en, const float* __restrict__ n_new,
    float* __restrict__ cbn_out, const float* __restrict__ loss_sum,
    float* __restrict__ loss_out) {
  int k = blockIdx.x;
  int d = threadIdx.x;
  size_t idx = (size_t)k * DIM + d;
  cbn_out[idx] = en[idx] / n_new[k];
  if (k == 0 && d == 0) loss_out[0] = 0.25f * loss_sum[0] / 33554432.0f;
}

extern "C" void kernel_launch(void* const* d_in, const int* in_sizes, int n_in,
                              void* d_out, int out_size, void* d_ws, size_t ws_size,
                              hipStream_t stream) {
  const float* z = (const float*)d_in[0];
  const float* cb = (const float*)d_in[1];
  const float* n_i = (const float*)d_in[2];
  const float* e_i = (const float*)d_in[3];

  float* out = (float*)d_out;
  float* out_code = out;                    // 33554432
  float* out_loss = out + 33554432;         // 1
  float* out_enc = out + 33554433;          // 131072
  float* out_cbn = out + 33685505;          // 131072
  float* out_nn = out + 33816577;           // 512
  float* out_en = out + 33817089;           // 131072

  char* ws = (char*)d_ws;
  float* cnorm = (float*)(ws + 0);
  int* counts = (int*)(ws + 2048);
  int* cursor = (int*)(ws + 6144);
  float* loss = (float*)(ws + 8192);
  int* enc_int = (int*)(ws + 12288);
  int* rowlist = (int*)(ws + 536576);

  // zero counts + loss (ws is poisoned 0xAA before each launch)
  hipMemsetAsync(ws + 2048, 0, 8192 - 2048 + 4, stream);

  cnorm_kernel<<<KCODES, 256, 0, stream>>>(cb, e_i, cnorm, out_en);
  argmin_kernel<<<NROWS / BM, 256, 0, stream>>>(z, cb, cnorm, enc_int, out_enc, counts);
  gather_kernel<<<(NROWS * (DIM / 4)) / 256, 256, 0, stream>>>(z, cb, enc_int, out_code, loss);
  scan_kernel<<<1, KCODES, 0, stream>>>(counts, n_i, out_nn, cursor);
  scatter_kernel<<<NROWS / 256, 256, 0, stream>>>(enc_int, cursor, rowlist);
  chunk_sum_kernel<<<NROWS / CHUNK, 256, 0, stream>>>(z, rowlist, out_en);
  finalize_kernel<<<KCODES, 256, 0, stream>>>(out_en, out_nn, out_cbn, loss, out_loss);
}

// Round 3
// 682.675 us; speedup vs baseline: 2.7896x; 1.5342x over previous
//
#include <hip/hip_runtime.h>
#include <cfloat>

#define NROWS 131072
#define DIM 256
#define KCODES 512
#define DECAYF 0.99f
#define OMDECAYF 0.01f
#define EPSF 1e-5f
#define BATCHF 32.0f

#define BM 128
#define BN 128
#define BD 16
#define LW 140  // LDS row width: mult of 4 (b128 align), LW%8==4 so d4-group writes are 2-way (free)
#define SW(c) ((c) + (((c) >> 5) << 2))  // B-column swizzle: spreads tx-groups 4-way -> 2-way
#define CHUNK 128
#define ROWMASK 0x1FFFF
#define GBLOCKS 1024

// ---------------- ws layout (bytes) ----------------
// 0      : cnorm       512 f
// 2048   : counts      512 i   (memset 0 each launch)
// 6144   : cursor      512 i   (written by scan)
// 8192   : loss_part   1024 f  (written by gather, reduced in scan)
// 12288  : enc_int     131072 i
// 536576 : rowlist     131072 i  (packed (code<<17)|row, sorted by code)

// cnorm + init e_new output with decay*e_i  (512 blocks x 256 = K x D exactly)
__global__ __launch_bounds__(256) void cnorm_kernel(const float* __restrict__ cb,
                                                    const float* __restrict__ e_i,
                                                    float* __restrict__ cnorm,
                                                    float* __restrict__ en_out) {
  int k = blockIdx.x;
  int t = threadIdx.x;
  size_t idx = (size_t)k * DIM + t;
  float v = cb[idx];
  en_out[idx] = DECAYF * e_i[idx];
  float s = v * v;
  for (int off = 32; off > 0; off >>= 1) s += __shfl_down(s, off);
  __shared__ float p[4];
  if ((t & 63) == 0) p[t >> 6] = s;
  __syncthreads();
  if (t == 0) cnorm[k] = (p[0] + p[1]) + (p[2] + p[3]);
}

// Fused distance-GEMM + argmin + histogram.
// Block: 256 threads = 16(tx: codes) x 16(ty: rows); micro-tile 8 rows x 8 codes.
__global__ __launch_bounds__(256) void argmin_kernel(
    const float* __restrict__ z, const float* __restrict__ cb,
    const float* __restrict__ cnorm, int* __restrict__ enc_int,
    float* __restrict__ enc_out, int* __restrict__ counts) {
  __shared__ float As[BD][LW];
  __shared__ float Bs[BD][LW];
  __shared__ int hist[KCODES];
  __shared__ float redv[BM][17];
  __shared__ int redi[BM][17];

  const int tid = threadIdx.x;
  const int tx = tid & 15;
  const int ty = tid >> 4;

  hist[tid] = 0;
  hist[tid + 256] = 0;

  const float* zblk = z + (size_t)blockIdx.x * BM * DIM;

  float minv[8];
  int mini[8];
#pragma unroll
  for (int r = 0; r < 8; ++r) { minv[r] = FLT_MAX; mini[r] = 0; }

  for (int cc = 0; cc < KCODES / BN; ++cc) {
    float acc[8][8];
#pragma unroll
    for (int r = 0; r < 8; ++r)
#pragma unroll
      for (int j = 0; j < 8; ++j) acc[r][j] = 0.f;

    for (int dc = 0; dc < DIM / BD; ++dc) {
      __syncthreads();
#pragma unroll
      for (int i = 0; i < 2; ++i) {
        int f4 = tid + i * 256;
        int r = f4 >> 2;
        int d4 = (f4 & 3) << 2;
        float4 av = *(const float4*)&zblk[(size_t)r * DIM + dc * BD + d4];
        As[d4 + 0][r] = av.x; As[d4 + 1][r] = av.y;
        As[d4 + 2][r] = av.z; As[d4 + 3][r] = av.w;
        float4 bv = *(const float4*)&cb[(size_t)(cc * BN + r) * DIM + dc * BD + d4];
        int rs = SW(r);
        Bs[d4 + 0][rs] = bv.x; Bs[d4 + 1][rs] = bv.y;
        Bs[d4 + 2][rs] = bv.z; Bs[d4 + 3][rs] = bv.w;
      }
      __syncthreads();
#pragma unroll 4
      for (int dd = 0; dd < BD; ++dd) {
        float a[8], b[8];
        *(float4*)&a[0] = *(const float4*)&As[dd][ty * 8];
        *(float4*)&a[4] = *(const float4*)&As[dd][ty * 8 + 4];
        *(float4*)&b[0] = *(const float4*)&Bs[dd][SW(tx * 8)];
        *(float4*)&b[4] = *(const float4*)&Bs[dd][SW(tx * 8 + 4)];
#pragma unroll
        for (int r = 0; r < 8; ++r)
#pragma unroll
          for (int j = 0; j < 8; ++j) acc[r][j] = fmaf(a[r], b[j], acc[r][j]);
      }
    }
    // score = ||c||^2 - 2*dot  (||x||^2 constant per row, irrelevant for argmin)
#pragma unroll
    for (int j = 0; j < 8; ++j) {
      int code = cc * BN + tx * 8 + j;
      float cn = cnorm[code];
#pragma unroll
      for (int r = 0; r < 8; ++r) {
        float s = cn - 2.f * acc[r][j];
        if (s < minv[r]) { minv[r] = s; mini[r] = code; }  // strict <: first occurrence wins
      }
    }
  }

  __syncthreads();
#pragma unroll
  for (int r = 0; r < 8; ++r) {
    redv[ty * 8 + r][tx] = minv[r];
    redi[ty * 8 + r][tx] = mini[r];
  }
  __syncthreads();
  if (tid < BM) {
    float bv = redv[tid][0];
    int bi = redi[tid][0];
#pragma unroll
    for (int t = 1; t < 16; ++t) {
      float v = redv[tid][t];
      int ii = redi[tid][t];
      if (v < bv || (v == bv && ii < bi)) { bv = v; bi = ii; }
    }
    int row = blockIdx.x * BM + tid;
    enc_int[row] = bi;
    enc_out[row] = (float)bi;
    atomicAdd(&hist[bi], 1);
  }
  __syncthreads();
  atomicAdd(&counts[tid], hist[tid]);
  atomicAdd(&counts[tid + 256], hist[tid + 256]);
}

// code gather -> code_ste output, per-block loss partials (NO same-address atomics)
__global__ __launch_bounds__(256) void gather_kernel(
    const float* __restrict__ z, const float* __restrict__ cb,
    const int* __restrict__ enc, float* __restrict__ code_out,
    float* __restrict__ loss_part) {
  const int per_block = (NROWS * (DIM / 4)) / GBLOCKS;  // 8192 float4s
  int base = blockIdx.x * per_block;
  float s = 0.f;
  for (int it = 0; it < per_block; it += 256) {
    int e4 = base + it + threadIdx.x;
    int row = e4 >> 6;        // 64 float4 per row
    int d4 = (e4 & 63) << 2;
    int k = enc[row];
    float4 zv = *(const float4*)&z[(size_t)e4 * 4];
    float4 cv = *(const float4*)&cb[(size_t)k * DIM + d4];
    *(float4*)&code_out[(size_t)e4 * 4] = cv;
    float dx = zv.x - cv.x, dy = zv.y - cv.y, dz = zv.z - cv.z, dw = zv.w - cv.w;
    s += dx * dx + dy * dy + dz * dz + dw * dw;
  }
  for (int off = 32; off > 0; off >>= 1) s += __shfl_down(s, off);
  __shared__ float p[4];
  int t = threadIdx.x;
  if ((t & 63) == 0) p[t >> 6] = s;
  __syncthreads();
  if (t == 0) loss_part[blockIdx.x] = (p[0] + p[1]) + (p[2] + p[3]);
}

// single block: n_new + exclusive prefix sum of counts -> cursor; loss reduce
__global__ __launch_bounds__(512) void scan_kernel(
    const int* __restrict__ counts, const float* __restrict__ n_i,
    float* __restrict__ n_new_out, int* __restrict__ cursor,
    const float* __restrict__ loss_part, float* __restrict__ loss_out) {
  __shared__ int sd[KCODES];
  int t = threadIdx.x;
  int c = counts[t];
  float nn = DECAYF * n_i[t] + OMDECAYF * (float)c;
  nn = (nn + EPSF) / (BATCHF + (float)KCODES * EPSF) * BATCHF;
  n_new_out[t] = nn;
  sd[t] = c;
  __syncthreads();
  for (int off = 1; off < KCODES; off <<= 1) {
    int v = (t >= off) ? sd[t - off] : 0;
    __syncthreads();
    sd[t] += v;
    __syncthreads();
  }
  cursor[t] = sd[t] - c;
  // loss reduction: 1024 partials over 512 threads
  float ls = loss_part[t] + loss_part[t + 512];
  for (int off = 32; off > 0; off >>= 1) ls += __shfl_down(ls, off);
  __shared__ float lp[8];
  if ((t & 63) == 0) lp[t >> 6] = ls;
  __syncthreads();
  if (t == 0) {
    float tot = 0.f;
#pragma unroll
    for (int i = 0; i < 8; ++i) tot += lp[i];
    loss_out[0] = 0.25f * tot / 33554432.0f;
  }
}

// LDS-aggregated counting-sort scatter: writes packed (code<<17)|row.
__global__ __launch_bounds__(256) void scatter_kernel(
    const int* __restrict__ enc, int* __restrict__ cursor,
    int* __restrict__ rowlist) {
  __shared__ int lcnt[KCODES];
  __shared__ int lbase[KCODES];
  int tid = threadIdx.x;
  int row = blockIdx.x * 256 + tid;
  lcnt[tid] = 0;
  lcnt[tid + 256] = 0;
  __syncthreads();
  int k = enc[row];
  int p = atomicAdd(&lcnt[k], 1);
  __syncthreads();
  int c0 = lcnt[tid];
  if (c0) lbase[tid] = atomicAdd(&cursor[tid], c0);
  int c1 = lcnt[tid + 256];
  if (c1) lbase[tid + 256] = atomicAdd(&cursor[tid + 256], c1);
  __syncthreads();
  rowlist[lbase[k] + p] = (k << 17) | row;
}

// Load-balanced segmented sum over sorted rowlist: 128 rows per block,
// run-length accumulate in registers, one atomicAdd per run per dim.
__global__ __launch_bounds__(256) void chunk_sum_kernel(
    const float* __restrict__ z, const int* __restrict__ rowlist,
    float* __restrict__ en_out) {
  __shared__ int rl[CHUNK];
  int tid = threadIdx.x;
  int d = tid;
  if (tid < CHUNK) rl[tid] = rowlist[blockIdx.x * CHUNK + tid];
  __syncthreads();
  int cur = rl[0] >> 17;
  float s = 0.f;
  for (int i = 0; i < CHUNK; i += 4) {
    int p0 = rl[i + 0], p1 = rl[i + 1], p2 = rl[i + 2], p3 = rl[i + 3];
    float v0 = z[(size_t)(p0 & ROWMASK) * DIM + d];
    float v1 = z[(size_t)(p1 & ROWMASK) * DIM + d];
    float v2 = z[(size_t)(p2 & ROWMASK) * DIM + d];
    float v3 = z[(size_t)(p3 & ROWMASK) * DIM + d];
    int k;
    k = p0 >> 17;
    if (k != cur) { atomicAdd(&en_out[(size_t)cur * DIM + d], OMDECAYF * s); s = 0.f; cur = k; }
    s += v0;
    k = p1 >> 17;
    if (k != cur) { atomicAdd(&en_out[(size_t)cur * DIM + d], OMDECAYF * s); s = 0.f; cur = k; }
    s += v1;
    k = p2 >> 17;
    if (k != cur) { atomicAdd(&en_out[(size_t)cur * DIM + d], OMDECAYF * s); s = 0.f; cur = k; }
    s += v2;
    k = p3 >> 17;
    if (k != cur) { atomicAdd(&en_out[(size_t)cur * DIM + d], OMDECAYF * s); s = 0.f; cur = k; }
    s += v3;
  }
  atomicAdd(&en_out[(size_t)cur * DIM + d], OMDECAYF * s);
}

// cbn = e_new / n_new
__global__ __launch_bounds__(256) void finalize_kernel(
    const float* __restrict__ en, const float* __restrict__ n_new,
    float* __restrict__ cbn_out) {
  int k = blockIdx.x;
  int d = threadIdx.x;
  size_t idx = (size_t)k * DIM + d;
  cbn_out[idx] = en[idx] / n_new[k];
}

extern "C" void kernel_launch(void* const* d_in, const int* in_sizes, int n_in,
                              void* d_out, int out_size, void* d_ws, size_t ws_size,
                              hipStream_t stream) {
  const float* z = (const float*)d_in[0];
  const float* cb = (const float*)d_in[1];
  const float* n_i = (const float*)d_in[2];
  const float* e_i = (const float*)d_in[3];

  float* out = (float*)d_out;
  float* out_code = out;                    // 33554432
  float* out_loss = out + 33554432;         // 1
  float* out_enc = out + 33554433;          // 131072
  float* out_cbn = out + 33685505;          // 131072
  float* out_nn = out + 33816577;           // 512
  float* out_en = out + 33817089;           // 131072

  char* ws = (char*)d_ws;
  float* cnorm = (float*)(ws + 0);
  int* counts = (int*)(ws + 2048);
  int* cursor = (int*)(ws + 6144);
  float* loss_part = (float*)(ws + 8192);
  int* enc_int = (int*)(ws + 12288);
  int* rowlist = (int*)(ws + 536576);

  // zero counts (ws is poisoned 0xAA before each launch)
  hipMemsetAsync(ws + 2048, 0, 2048, stream);

  cnorm_kernel<<<KCODES, 256, 0, stream>>>(cb, e_i, cnorm, out_en);
  argmin_kernel<<<NROWS / BM, 256, 0, stream>>>(z, cb, cnorm, enc_int, out_enc, counts);
  gather_kernel<<<GBLOCKS, 256, 0, stream>>>(z, cb, enc_int, out_code, loss_part);
  scan_kernel<<<1, KCODES, 0, stream>>>(counts, n_i, out_nn, cursor, loss_part, out_loss);
  scatter_kernel<<<NROWS / 256, 256, 0, stream>>>(enc_int, cursor, rowlist);
  chunk_sum_kernel<<<NROWS / CHUNK, 256, 0, stream>>>(z, rowlist, out_en);
  finalize_kernel<<<KCODES, 256, 0, stream>>>(out_en, out_nn, out_cbn);
}